// Round 4
// baseline (4105.891 us; speedup 1.0000x reference)
//
#include <hip/hip_runtime.h>
#include <math.h>

typedef unsigned int uint;
typedef unsigned short ushort;

#define NROWS 65536
#define KCB   1024
#define DDIM  256
#define MARGIN 0.01f

// d_out layout (floats)
#define OUT_ZQ    0
#define OUT_LOSS  16777216
#define OUT_IDX   16777217
#define OUT_PERP  16842753
#define OUT_USAGE 16842754

typedef __attribute__((ext_vector_type(8)))  short s16x8;
typedef __attribute__((ext_vector_type(16))) float f32x16;

__device__ __forceinline__ ushort bf16rne(float x) {
  uint u = __float_as_uint(x);
  return (ushort)((u + 0x7FFFu + ((u >> 16) & 1u)) >> 16);
}
__device__ __forceinline__ float bf2f(ushort h) {
  return __uint_as_float((uint)h << 16);
}

// ---------------------------------------------------------------------------
// Kernel 1: codebook = normalize(lb @ W.T) * 16 in fp64; emit fp64, fp32,
// and bf16 hi/lo split copies.
// ---------------------------------------------------------------------------
__global__ __launch_bounds__(256) void cb_kernel(const float* __restrict__ lb,
                                                 const float* __restrict__ W,
                                                 double* __restrict__ cb64,
                                                 float* __restrict__ cb32,
                                                 double* __restrict__ c264,
                                                 ushort* __restrict__ ch,
                                                 ushort* __restrict__ cl) {
  const int k = blockIdx.x;
  const int t = threadIdx.x;
  __shared__ float lb_sh[256];
  __shared__ float W_sh[256 * 66];
  __shared__ double red[256];

  lb_sh[t] = lb[k * 256 + t];

  double acc = 0.0;
  for (int jt = 0; jt < 4; ++jt) {
    __syncthreads();
#pragma unroll
    for (int i = 0; i < 16; ++i) {
      int qid = t + 256 * i;
      int row = qid >> 4;
      int q   = qid & 15;
      float4 v = *(const float4*)&W[row * 256 + jt * 64 + q * 4];
      float* dst = &W_sh[row * 66 + q * 4];
      dst[0] = v.x; dst[1] = v.y; dst[2] = v.z; dst[3] = v.w;
    }
    __syncthreads();
#pragma unroll
    for (int jj = 0; jj < 64; ++jj) {
      acc += (double)lb_sh[jt * 64 + jj] * (double)W_sh[t * 66 + jj];
    }
  }

  red[t] = acc * acc;
  __syncthreads();
  for (int s = 128; s > 0; s >>= 1) {
    if (t < s) red[t] += red[t + s];
    __syncthreads();
  }
  double norm  = sqrt(red[0]);
  double scale = 16.0 / fmax(norm, 1e-12);
  double v     = acc * scale;
  cb64[k * 256 + t] = v;
  float cf = (float)v;
  cb32[k * 256 + t] = cf;
  ushort hh = bf16rne(cf);
  ch[k * 256 + t] = hh;
  cl[k * 256 + t] = bf16rne(cf - bf2f(hh));

  __syncthreads();
  red[t] = v * v;
  __syncthreads();
  for (int s = 128; s > 0; s >>= 1) {
    if (t < s) red[t] += red[t + s];
    __syncthreads();
  }
  if (t == 0) c264[k] = red[0];
}

// ---------------------------------------------------------------------------
// Kernel 1b: split z fp32 -> z_hi + z_lo bf16.
// ---------------------------------------------------------------------------
__global__ __launch_bounds__(256) void zsplit_kernel(const float* __restrict__ z,
                                                     ushort* __restrict__ zhi,
                                                     ushort* __restrict__ zlo) {
  int i = blockIdx.x * 256 + threadIdx.x;
  const int stride = gridDim.x * 256;
  const int nq = NROWS * DDIM / 4;
  for (; i < nq; i += stride) {
    float4 v = *(const float4*)&z[i * 4];
    ushort4 h, l;
    h.x = bf16rne(v.x); l.x = bf16rne(v.x - bf2f(h.x));
    h.y = bf16rne(v.y); l.y = bf16rne(v.y - bf2f(h.y));
    h.z = bf16rne(v.z); l.z = bf16rne(v.z - bf2f(h.z));
    h.w = bf16rne(v.w); l.w = bf16rne(v.w - bf2f(h.w));
    *(ushort4*)&zhi[i * 4] = h;
    *(ushort4*)&zlo[i * 4] = l;
  }
}

// ---------------------------------------------------------------------------
// Kernel 2: fused MFMA argmax + gather. Block = 128 rows x ALL 1024 codes.
// nt loop (8 x 128-code tiles) outer, kt loop (8 x K=32) inner, double-
// buffered LDS (2 x 32KB), 2-phase pipeline.
// Fix vs round 3: waves wn=0 and wn=1 cover DIFFERENT 64-code halves of
// every nt tile, so after the in-wave butterfly their states must be merged
// across wn (via small LDS arrays, compile-time-indexed register access);
// only wn=0 waves write final outputs / flags (no write race, no duplicate
// flag entries).
// ---------------------------------------------------------------------------
template <bool PRESPLIT>
__global__ __launch_bounds__(256, 2) void argmax_mfma(const float* __restrict__ z,
                                                      const ushort* __restrict__ zhi,
                                                      const ushort* __restrict__ zlo,
                                                      const ushort* __restrict__ ch,
                                                      const ushort* __restrict__ cl,
                                                      const float* __restrict__ cb32,
                                                      float* __restrict__ out_idx,
                                                      int* __restrict__ idx_int,
                                                      int* __restrict__ flagc,
                                                      int* __restrict__ flagr,
                                                      float* __restrict__ zq,
                                                      double* __restrict__ msep,
                                                      int* __restrict__ counts) {
  const int t     = threadIdx.x;
  const int lane  = t & 63;
  const int w     = t >> 6;
  const int wm    = w >> 1, wn = w & 1;
  const int mtile = blockIdx.x;

  __shared__ alignas(128) char smem[2][4][8192];  // [buf][ZH,ZL,CH,CL]
  __shared__ double partial[4];
  __shared__ float  xm1[2][2][32];   // [wm][half][idx]  (wn=1 publish)
  __shared__ int    xi1[2][2][32];
  __shared__ uint   xfl[2][2];
  __shared__ int    sidx[128];

  float m1[32];
  int   i1[32];
  uint  flags = 0;
#pragma unroll
  for (int i = 0; i < 32; ++i) { m1[i] = -3.0e38f; i1[i] = 0; }

  // ---- staging ----
  auto stage = [&](int buf, int nt, int kt) {
    if (PRESPLIT) {
      const ushort* sb = (w == 0) ? zhi : (w == 1) ? zlo : (w == 2) ? ch : cl;
      const int rowbase = (w < 2) ? (mtile * 128) : (nt * 128);
      char* dstbase = &smem[buf][w][0];
      const int r = lane >> 2;
      const int q = lane & 3;
#pragma unroll
      for (int i = 0; i < 8; ++i) {
        int rr = i * 16 + r;
        int qs = q ^ (rr & 3) ^ ((rr >> 2) & 1);
        const ushort* src = sb + (size_t)(rowbase + rr) * 256 + kt * 32 + qs * 8;
        __builtin_amdgcn_global_load_lds((const __attribute__((address_space(1))) void*)src,
                                         (__attribute__((address_space(3))) void*)(dstbase + i * 1024),
                                         16, 0, 0);
      }
    } else {
      {
        const ushort* sb = (w < 2) ? ch : cl;
        char* dstbase = &smem[buf][2 + (w >> 1)][0] + (w & 1) * 4096;
        const int r = lane >> 2, q = lane & 3;
#pragma unroll
        for (int i = 0; i < 4; ++i) {
          int rr = (w & 1) * 64 + i * 16 + r;
          int qs = q ^ (rr & 3) ^ ((rr >> 2) & 1);
          const ushort* src = sb + (size_t)(nt * 128 + rr) * 256 + kt * 32 + qs * 8;
          __builtin_amdgcn_global_load_lds((const __attribute__((address_space(1))) void*)src,
                                           (__attribute__((address_space(3))) void*)(dstbase + i * 1024),
                                           16, 0, 0);
        }
      }
      {
        const int r = t >> 1, kh = t & 1;
        const float* zp = z + (size_t)(mtile * 128 + r) * 256 + kt * 32 + kh * 16;
        float4 f0 = *(const float4*)(zp);
        float4 f1 = *(const float4*)(zp + 4);
        float4 f2 = *(const float4*)(zp + 8);
        float4 f3 = *(const float4*)(zp + 12);
        float xs[16] = {f0.x, f0.y, f0.z, f0.w, f1.x, f1.y, f1.z, f1.w,
                        f2.x, f2.y, f2.z, f2.w, f3.x, f3.y, f3.z, f3.w};
        s16x8 h0, l0, h1, l1;
#pragma unroll
        for (int e = 0; e < 8; ++e) {
          ushort hh = bf16rne(xs[e]);
          h0[e] = (short)hh;
          l0[e] = (short)bf16rne(xs[e] - bf2f(hh));
        }
#pragma unroll
        for (int e = 0; e < 8; ++e) {
          ushort hh = bf16rne(xs[8 + e]);
          h1[e] = (short)hh;
          l1[e] = (short)bf16rne(xs[8 + e] - bf2f(hh));
        }
        const int sw = (r & 3) ^ ((r >> 2) & 1);
        const int s0 = (kh * 2) ^ sw, s1 = (kh * 2 + 1) ^ sw;
        *(s16x8*)(&smem[buf][0][0] + r * 64 + s0 * 16) = h0;
        *(s16x8*)(&smem[buf][1][0] + r * 64 + s0 * 16) = l0;
        *(s16x8*)(&smem[buf][0][0] + r * 64 + s1 * 16) = h1;
        *(s16x8*)(&smem[buf][1][0] + r * 64 + s1 * 16) = l1;
      }
    }
  };

  // ---- main loop ----
  stage(0, 0, 0);
  __syncthreads();

#pragma unroll 1
  for (int nt = 0; nt < 8; ++nt) {
    f32x16 a00 = 0.0f, a01 = 0.0f, a10 = 0.0f, a11 = 0.0f;
#pragma unroll
    for (int kt = 0; kt < 8; ++kt) {
      const int cur = kt & 1;
      if (kt < 7)      stage(cur ^ 1, nt, kt + 1);
      else if (nt < 7) stage(cur ^ 1, nt + 1, 0);

#pragma unroll
      for (int ks = 0; ks < 2; ++ks) {
        const int s  = ks * 2 + (lane >> 5);
        const int ra = lane & 31;
        auto frag = [&](int tile, int row) -> s16x8 {
          int slot = s ^ (row & 3) ^ ((row >> 2) & 1);
          return *(const s16x8*)(&smem[cur][tile][0] + row * 64 + slot * 16);
        };
        s16x8 ah0 = frag(0, wm * 64 + ra);
        s16x8 ah1 = frag(0, wm * 64 + 32 + ra);
        s16x8 al0 = frag(1, wm * 64 + ra);
        s16x8 al1 = frag(1, wm * 64 + 32 + ra);
        s16x8 bh0 = frag(2, wn * 64 + ra);
        s16x8 bh1 = frag(2, wn * 64 + 32 + ra);
        s16x8 bl0 = frag(3, wn * 64 + ra);
        s16x8 bl1 = frag(3, wn * 64 + 32 + ra);
        a00 = __builtin_amdgcn_mfma_f32_32x32x16_bf16(ah0, bh0, a00, 0, 0, 0);
        a01 = __builtin_amdgcn_mfma_f32_32x32x16_bf16(ah0, bh1, a01, 0, 0, 0);
        a10 = __builtin_amdgcn_mfma_f32_32x32x16_bf16(ah1, bh0, a10, 0, 0, 0);
        a11 = __builtin_amdgcn_mfma_f32_32x32x16_bf16(ah1, bh1, a11, 0, 0, 0);
        a00 = __builtin_amdgcn_mfma_f32_32x32x16_bf16(al0, bh0, a00, 0, 0, 0);
        a01 = __builtin_amdgcn_mfma_f32_32x32x16_bf16(al0, bh1, a01, 0, 0, 0);
        a10 = __builtin_amdgcn_mfma_f32_32x32x16_bf16(al1, bh0, a10, 0, 0, 0);
        a11 = __builtin_amdgcn_mfma_f32_32x32x16_bf16(al1, bh1, a11, 0, 0, 0);
        a00 = __builtin_amdgcn_mfma_f32_32x32x16_bf16(ah0, bl0, a00, 0, 0, 0);
        a01 = __builtin_amdgcn_mfma_f32_32x32x16_bf16(ah0, bl1, a01, 0, 0, 0);
        a10 = __builtin_amdgcn_mfma_f32_32x32x16_bf16(ah1, bl0, a10, 0, 0, 0);
        a11 = __builtin_amdgcn_mfma_f32_32x32x16_bf16(ah1, bl1, a11, 0, 0, 0);
      }
      __syncthreads();
    }

    // fold this nt's codes into running per-lane state (register-only)
    const int cbase = nt * 128 + wn * 64 + (lane & 31);
#define FOLD(IDX, V, C)                                                        \
    {                                                                          \
      float v_ = (V);                                                          \
      if (fabsf(v_ - m1[IDX]) < MARGIN) flags |= (1u << (IDX));                \
      if (v_ > m1[IDX]) { i1[IDX] = (C); m1[IDX] = v_; }                       \
    }
#pragma unroll
    for (int p = 0; p < 16; ++p) {
      FOLD(p,      a00[p], cbase);
      FOLD(p,      a01[p], cbase + 32);
      FOLD(16 + p, a10[p], cbase);
      FOLD(16 + p, a11[p], cbase + 32);
    }
#undef FOLD
  }

  // ---- cross-lane reduce over the 32 column-lanes (within wave) ----
#pragma unroll
  for (int off = 1; off <= 16; off <<= 1) {
    uint nf = flags | (uint)__shfl_xor((int)flags, off);
#pragma unroll
    for (int idx = 0; idx < 32; ++idx) {
      float om = __shfl_xor(m1[idx], off);
      int   oi = __shfl_xor(i1[idx], off);
      if (fabsf(om - m1[idx]) < MARGIN) nf |= (1u << idx);
      if (om > m1[idx] || (om == m1[idx] && oi < i1[idx])) { m1[idx] = om; i1[idx] = oi; }
    }
    flags = nf;
  }

  // ---- cross-wn merge: wn=1 publishes, wn=0 merges + writes ----
  if (wn == 1 && (lane & 31) == 0) {
    const int half = lane >> 5;
#pragma unroll
    for (int idx = 0; idx < 32; ++idx) {
      xm1[wm][half][idx] = m1[idx];
      xi1[wm][half][idx] = i1[idx];
    }
    xfl[wm][half] = flags;
  }
  __syncthreads();
  if (wn == 0 && (lane & 31) == 0) {
    const int half = lane >> 5;
    flags |= xfl[wm][half];
#pragma unroll
    for (int idx = 0; idx < 32; ++idx) {
      float om = xm1[wm][half][idx];
      int   oi = xi1[wm][half][idx];
      if (fabsf(om - m1[idx]) < MARGIN) flags |= (1u << idx);
      if (om > m1[idx] || (om == m1[idx] && oi < i1[idx])) { m1[idx] = om; i1[idx] = oi; }
    }
#pragma unroll
    for (int idx = 0; idx < 32; ++idx) {
      int p = idx & 15;
      int lrow = wm * 64 + (idx >> 4) * 32 + (p & 3) + 8 * (p >> 2) + 4 * half;
      int row  = mtile * 128 + lrow;
      sidx[lrow]   = i1[idx];
      idx_int[row] = i1[idx];
      out_idx[row] = (float)i1[idx];
      if (flags & (1u << idx)) {
        int pos = atomicAdd(flagc, 1);
        flagr[pos] = row;
      }
    }
  }
  __syncthreads();

  // ---- fused gather: z_q write, mse partial, counts ----
  double msum = 0.0;
  for (int rr = w; rr < 128; rr += 4) {
    const int code = sidx[rr];
    const int grow = mtile * 128 + rr;
    float4 c = *(const float4*)&cb32[(size_t)code * 256 + lane * 4];
    *(float4*)&zq[(size_t)grow * 256 + lane * 4] = c;
    float4 zr;
    if (PRESPLIT) {
      ushort4 h = *(const ushort4*)&zhi[(size_t)grow * 256 + lane * 4];
      ushort4 l = *(const ushort4*)&zlo[(size_t)grow * 256 + lane * 4];
      zr.x = bf2f(h.x) + bf2f(l.x);
      zr.y = bf2f(h.y) + bf2f(l.y);
      zr.z = bf2f(h.z) + bf2f(l.z);
      zr.w = bf2f(h.w) + bf2f(l.w);
    } else {
      zr = *(const float4*)&z[(size_t)grow * 256 + lane * 4];
    }
    double d;
    d = (double)c.x - (double)zr.x; msum += d * d;
    d = (double)c.y - (double)zr.y; msum += d * d;
    d = (double)c.z - (double)zr.z; msum += d * d;
    d = (double)c.w - (double)zr.w; msum += d * d;
    if (lane == 0) atomicAdd(&counts[code], 1);
  }
#pragma unroll
  for (int off = 32; off > 0; off >>= 1) msum += __shfl_xor(msum, off);
  if (lane == 0) partial[w] = msum;
  __syncthreads();
  if (t == 0) msep[mtile] = partial[0] + partial[1] + partial[2] + partial[3];
}

// ---------------------------------------------------------------------------
// Kernel 3: exact fp64 re-solve of flagged rows; patches idx, z_q, counts,
// and accumulates the mse delta for rows whose index changes.
// ---------------------------------------------------------------------------
__global__ __launch_bounds__(256) void refine_kernel(const float* __restrict__ z,
                                                     const double* __restrict__ cb64,
                                                     const double* __restrict__ c264,
                                                     const float* __restrict__ cb32,
                                                     const int* __restrict__ flagc,
                                                     const int* __restrict__ flagr,
                                                     int* __restrict__ idx_int,
                                                     float* __restrict__ out_idx,
                                                     float* __restrict__ zq,
                                                     int* __restrict__ counts,
                                                     double* __restrict__ msedelta) {
  const int cnt  = *flagc;
  const int t    = threadIdx.x;
  const int w    = t >> 6;
  const int lane = t & 63;
  __shared__ double bs[4];
  __shared__ int    bi[4];
  __shared__ int    shI, shO;
  __shared__ double red[256];

  for (int fi = blockIdx.x; fi < cnt; fi += gridDim.x) {
    const int row = flagr[fi];
    double zr[4];
#pragma unroll
    for (int jj = 0; jj < 4; ++jj)
      zr[jj] = (double)z[row * DDIM + jj * 64 + lane];

    double best = -1e300;
    int bidx = 0;
    for (int k = w * 256; k < w * 256 + 256; ++k) {
      double p = 0.0;
#pragma unroll
      for (int jj = 0; jj < 4; ++jj)
        p += zr[jj] * cb64[k * DDIM + jj * 64 + lane];
#pragma unroll
      for (int off = 32; off > 0; off >>= 1) p += __shfl_xor(p, off);
      double sc = 2.0 * p - c264[k];
      if (sc > best) { best = sc; bidx = k; }   // ascending k: tie -> smaller
    }
    if (lane == 0) { bs[w] = best; bi[w] = bidx; }
    __syncthreads();
    if (t == 0) {
      double B = bs[0]; int I = bi[0];
#pragma unroll
      for (int w2 = 1; w2 < 4; ++w2) {
        if (bs[w2] > B || (bs[w2] == B && bi[w2] < I)) { B = bs[w2]; I = bi[w2]; }
      }
      shO = idx_int[row];
      shI = I;
      if (I != shO) {
        idx_int[row] = I;
        out_idx[row] = (float)I;
        atomicSub(&counts[shO], 1);
        atomicAdd(&counts[I], 1);
      }
    }
    __syncthreads();
    const int I = shI, O = shO;
    if (I != O) {
      float zz = z[row * DDIM + t];
      float cn = cb32[I * DDIM + t];
      float co = cb32[O * DDIM + t];
      zq[(size_t)row * DDIM + t] = cn;
      double dn = (double)cn - (double)zz;
      double dd = (double)co - (double)zz;
      red[t] = dn * dn - dd * dd;
      __syncthreads();
      for (int s = 128; s > 0; s >>= 1) {
        if (t < s) red[t] += red[t + s];
        __syncthreads();
      }
      if (t == 0) atomicAdd(msedelta, red[0]);
    }
    __syncthreads();
  }
}

// ---------------------------------------------------------------------------
// Kernel 4: scalars -- vq_loss, perplexity, codebook_usage.
// ---------------------------------------------------------------------------
__global__ __launch_bounds__(256) void finalize_kernel(const int* __restrict__ counts,
                                                       const double* __restrict__ msep,
                                                       const double* __restrict__ msedelta,
                                                       float* __restrict__ out) {
  const int t = threadIdx.x;
  double ms = 0.0;
#pragma unroll
  for (int i = t; i < 512; i += 256) ms += msep[i];
  if (t == 0) ms += *msedelta;

  double ent = 0.0;
  int used = 0;
#pragma unroll
  for (int i = t; i < KCB; i += 256) {
    int c = counts[i];
    if (c > 0) used++;
    double p = (double)c / (double)NROWS;
    ent += p * log(p + 1e-10);
  }
  __shared__ double se[256];
  __shared__ double sm[256];
  __shared__ int    su[256];
  se[t] = ent; sm[t] = ms; su[t] = used;
  __syncthreads();
  for (int s = 128; s > 0; s >>= 1) {
    if (t < s) { se[t] += se[t + s]; sm[t] += sm[t + s]; su[t] += su[t + s]; }
    __syncthreads();
  }
  if (t == 0) {
    double mse = sm[0] / ((double)NROWS * (double)DDIM);
    out[OUT_LOSS]  = (float)(1.25 * mse);
    out[OUT_PERP]  = (float)exp(-se[0]);
    out[OUT_USAGE] = (float)((double)su[0] / (double)KCB);
  }
}

// ---------------------------------------------------------------------------
extern "C" void kernel_launch(void* const* d_in, const int* in_sizes, int n_in,
                              void* d_out, int out_size, void* d_ws, size_t ws_size,
                              hipStream_t stream) {
  const float* z  = (const float*)d_in[0];   // [65536][256]
  const float* lb = (const float*)d_in[1];   // [1024][256]
  const float* W  = (const float*)d_in[2];   // [256][256]
  float* out = (float*)d_out;

  const size_t NEEDED_FULL = 0x4490000;      // ~72 MB incl. z_hi/z_lo
  const bool presplit = ws_size >= NEEDED_FULL;

  char* ws = (char*)d_ws;
  ushort* zhi = (ushort*)(ws + 0x0000000);   // 32 MB (presplit only)
  ushort* zlo = (ushort*)(ws + 0x2000000);   // 32 MB (presplit only)
  char* base = ws + (presplit ? 0x4000000 : 0);

  double* cb64    = (double*)(base + 0x000000);  // 2 MB
  ushort* ch      = (ushort*)(base + 0x200000);  // 512 KB
  ushort* cl      = (ushort*)(base + 0x280000);  // 512 KB
  float*  cb32    = (float*) (base + 0x300000);  // 1 MB
  double* c264    = (double*)(base + 0x400000);  // 8 KB
  int*    idxi    = (int*)   (base + 0x402000);  // 256 KB
  int*    flagr   = (int*)   (base + 0x442000);  // 256 KB
  int*    flagc   = (int*)   (base + 0x482000);  // 4 B
  int*    counts  = (int*)   (base + 0x482100);  // 4 KB
  double* msep    = (double*)(base + 0x483100);  // 4 KB (512 doubles)
  double* msedel  = (double*)(base + 0x484100);  // 8 B

  hipMemsetAsync(flagc, 0, 4, stream);
  hipMemsetAsync(counts, 0, KCB * sizeof(int), stream);
  hipMemsetAsync(msedel, 0, sizeof(double), stream);

  cb_kernel<<<KCB, 256, 0, stream>>>(lb, W, cb64, cb32, c264, ch, cl);
  if (presplit) {
    zsplit_kernel<<<4096, 256, 0, stream>>>(z, zhi, zlo);
    argmax_mfma<true><<<NROWS / 128, 256, 0, stream>>>(z, zhi, zlo, ch, cl, cb32,
                                                       out + OUT_IDX, idxi, flagc, flagr,
                                                       out + OUT_ZQ, msep, counts);
  } else {
    argmax_mfma<false><<<NROWS / 128, 256, 0, stream>>>(z, zhi, zlo, ch, cl, cb32,
                                                        out + OUT_IDX, idxi, flagc, flagr,
                                                        out + OUT_ZQ, msep, counts);
  }
  refine_kernel<<<512, 256, 0, stream>>>(z, cb64, c264, cb32, flagc, flagr,
                                         idxi, out + OUT_IDX, out + OUT_ZQ,
                                         counts, msedel);
  finalize_kernel<<<1, 256, 0, stream>>>(counts, msep, msedel, out);
}

// Round 5
// 3609.438 us; speedup vs baseline: 1.1375x; 1.1375x over previous
//
#include <hip/hip_runtime.h>
#include <math.h>

typedef unsigned int uint;
typedef unsigned short ushort;

#define NROWS 65536
#define KCB   1024
#define DDIM  256
#define MARGIN 0.01f

// d_out layout (floats)
#define OUT_ZQ    0
#define OUT_LOSS  16777216
#define OUT_IDX   16777217
#define OUT_PERP  16842753
#define OUT_USAGE 16842754

typedef __attribute__((ext_vector_type(8)))  short s16x8;
typedef __attribute__((ext_vector_type(16))) float f32x16;

__device__ __forceinline__ ushort bf16rne(float x) {
  uint u = __float_as_uint(x);
  return (ushort)((u + 0x7FFFu + ((u >> 16) & 1u)) >> 16);
}
__device__ __forceinline__ float bf2f(ushort h) {
  return __uint_as_float((uint)h << 16);
}

// ---------------------------------------------------------------------------
// Kernel 1: codebook = normalize(lb @ W.T) * 16 in fp64; emit fp64, fp32,
// and bf16 hi/lo split copies.
// ---------------------------------------------------------------------------
__global__ __launch_bounds__(256) void cb_kernel(const float* __restrict__ lb,
                                                 const float* __restrict__ W,
                                                 double* __restrict__ cb64,
                                                 float* __restrict__ cb32,
                                                 double* __restrict__ c264,
                                                 ushort* __restrict__ ch,
                                                 ushort* __restrict__ cl) {
  const int k = blockIdx.x;
  const int t = threadIdx.x;
  __shared__ float lb_sh[256];
  __shared__ float W_sh[256 * 66];
  __shared__ double red[256];

  lb_sh[t] = lb[k * 256 + t];

  double acc = 0.0;
  for (int jt = 0; jt < 4; ++jt) {
    __syncthreads();
#pragma unroll
    for (int i = 0; i < 16; ++i) {
      int qid = t + 256 * i;
      int row = qid >> 4;
      int q   = qid & 15;
      float4 v = *(const float4*)&W[row * 256 + jt * 64 + q * 4];
      float* dst = &W_sh[row * 66 + q * 4];
      dst[0] = v.x; dst[1] = v.y; dst[2] = v.z; dst[3] = v.w;
    }
    __syncthreads();
#pragma unroll
    for (int jj = 0; jj < 64; ++jj) {
      acc += (double)lb_sh[jt * 64 + jj] * (double)W_sh[t * 66 + jj];
    }
  }

  red[t] = acc * acc;
  __syncthreads();
  for (int s = 128; s > 0; s >>= 1) {
    if (t < s) red[t] += red[t + s];
    __syncthreads();
  }
  double norm  = sqrt(red[0]);
  double scale = 16.0 / fmax(norm, 1e-12);
  double v     = acc * scale;
  cb64[k * 256 + t] = v;
  float cf = (float)v;
  cb32[k * 256 + t] = cf;
  ushort hh = bf16rne(cf);
  ch[k * 256 + t] = hh;
  cl[k * 256 + t] = bf16rne(cf - bf2f(hh));

  __syncthreads();
  red[t] = v * v;
  __syncthreads();
  for (int s = 128; s > 0; s >>= 1) {
    if (t < s) red[t] += red[t + s];
    __syncthreads();
  }
  if (t == 0) c264[k] = red[0];
}

// ---------------------------------------------------------------------------
// Kernel 1b: split z fp32 -> z_hi + z_lo bf16.
// ---------------------------------------------------------------------------
__global__ __launch_bounds__(256) void zsplit_kernel(const float* __restrict__ z,
                                                     ushort* __restrict__ zhi,
                                                     ushort* __restrict__ zlo) {
  int i = blockIdx.x * 256 + threadIdx.x;
  const int stride = gridDim.x * 256;
  const int nq = NROWS * DDIM / 4;
  for (; i < nq; i += stride) {
    float4 v = *(const float4*)&z[i * 4];
    ushort4 h, l;
    h.x = bf16rne(v.x); l.x = bf16rne(v.x - bf2f(h.x));
    h.y = bf16rne(v.y); l.y = bf16rne(v.y - bf2f(h.y));
    h.z = bf16rne(v.z); l.z = bf16rne(v.z - bf2f(h.z));
    h.w = bf16rne(v.w); l.w = bf16rne(v.w - bf2f(h.w));
    *(ushort4*)&zhi[i * 4] = h;
    *(ushort4*)&zlo[i * 4] = l;
  }
}

// ---------------------------------------------------------------------------
// Kernel 2: fused MFMA argmax + gather. Block = 128 rows x ALL 1024 codes.
// Round-5 fix: exact (m1, m2, i1) tracking everywhere (FOLD, butterfly,
// cross-wn merge); near-tie flag = (m1 - m2 < MARGIN) evaluated ONCE at the
// end. Round 4's running-prefix-margin criterion over-flagged ~60x and made
// refine_kernel the 3.2ms bottleneck.
// ---------------------------------------------------------------------------
template <bool PRESPLIT>
__global__ __launch_bounds__(256, 2) void argmax_mfma(const float* __restrict__ z,
                                                      const ushort* __restrict__ zhi,
                                                      const ushort* __restrict__ zlo,
                                                      const ushort* __restrict__ ch,
                                                      const ushort* __restrict__ cl,
                                                      const float* __restrict__ cb32,
                                                      float* __restrict__ out_idx,
                                                      int* __restrict__ idx_int,
                                                      int* __restrict__ flagc,
                                                      int* __restrict__ flagr,
                                                      float* __restrict__ zq,
                                                      double* __restrict__ msep,
                                                      int* __restrict__ counts) {
  const int t     = threadIdx.x;
  const int lane  = t & 63;
  const int w     = t >> 6;
  const int wm    = w >> 1, wn = w & 1;
  const int mtile = blockIdx.x;

  __shared__ alignas(128) char smem[2][4][8192];  // [buf][ZH,ZL,CH,CL]
  __shared__ double partial[4];
  __shared__ float  xm1[2][2][32];   // [wm][half][idx]  (wn=1 publish)
  __shared__ float  xm2[2][2][32];
  __shared__ int    xi1[2][2][32];
  __shared__ int    sidx[128];

  float m1[32], m2[32];
  int   i1[32];
#pragma unroll
  for (int i = 0; i < 32; ++i) { m1[i] = -3.0e38f; m2[i] = -3.0e38f; i1[i] = 0; }

  // ---- staging ----
  auto stage = [&](int buf, int nt, int kt) {
    if (PRESPLIT) {
      const ushort* sb = (w == 0) ? zhi : (w == 1) ? zlo : (w == 2) ? ch : cl;
      const int rowbase = (w < 2) ? (mtile * 128) : (nt * 128);
      char* dstbase = &smem[buf][w][0];
      const int r = lane >> 2;
      const int q = lane & 3;
#pragma unroll
      for (int i = 0; i < 8; ++i) {
        int rr = i * 16 + r;
        int qs = q ^ (rr & 3) ^ ((rr >> 2) & 1);
        const ushort* src = sb + (size_t)(rowbase + rr) * 256 + kt * 32 + qs * 8;
        __builtin_amdgcn_global_load_lds((const __attribute__((address_space(1))) void*)src,
                                         (__attribute__((address_space(3))) void*)(dstbase + i * 1024),
                                         16, 0, 0);
      }
    } else {
      {
        const ushort* sb = (w < 2) ? ch : cl;
        char* dstbase = &smem[buf][2 + (w >> 1)][0] + (w & 1) * 4096;
        const int r = lane >> 2, q = lane & 3;
#pragma unroll
        for (int i = 0; i < 4; ++i) {
          int rr = (w & 1) * 64 + i * 16 + r;
          int qs = q ^ (rr & 3) ^ ((rr >> 2) & 1);
          const ushort* src = sb + (size_t)(nt * 128 + rr) * 256 + kt * 32 + qs * 8;
          __builtin_amdgcn_global_load_lds((const __attribute__((address_space(1))) void*)src,
                                           (__attribute__((address_space(3))) void*)(dstbase + i * 1024),
                                           16, 0, 0);
        }
      }
      {
        const int r = t >> 1, kh = t & 1;
        const float* zp = z + (size_t)(mtile * 128 + r) * 256 + kt * 32 + kh * 16;
        float4 f0 = *(const float4*)(zp);
        float4 f1 = *(const float4*)(zp + 4);
        float4 f2 = *(const float4*)(zp + 8);
        float4 f3 = *(const float4*)(zp + 12);
        float xs[16] = {f0.x, f0.y, f0.z, f0.w, f1.x, f1.y, f1.z, f1.w,
                        f2.x, f2.y, f2.z, f2.w, f3.x, f3.y, f3.z, f3.w};
        s16x8 h0, l0, h1, l1;
#pragma unroll
        for (int e = 0; e < 8; ++e) {
          ushort hh = bf16rne(xs[e]);
          h0[e] = (short)hh;
          l0[e] = (short)bf16rne(xs[e] - bf2f(hh));
        }
#pragma unroll
        for (int e = 0; e < 8; ++e) {
          ushort hh = bf16rne(xs[8 + e]);
          h1[e] = (short)hh;
          l1[e] = (short)bf16rne(xs[8 + e] - bf2f(hh));
        }
        const int sw = (r & 3) ^ ((r >> 2) & 1);
        const int s0 = (kh * 2) ^ sw, s1 = (kh * 2 + 1) ^ sw;
        *(s16x8*)(&smem[buf][0][0] + r * 64 + s0 * 16) = h0;
        *(s16x8*)(&smem[buf][1][0] + r * 64 + s0 * 16) = l0;
        *(s16x8*)(&smem[buf][0][0] + r * 64 + s1 * 16) = h1;
        *(s16x8*)(&smem[buf][1][0] + r * 64 + s1 * 16) = l1;
      }
    }
  };

  // ---- main loop ----
  stage(0, 0, 0);
  __syncthreads();

#pragma unroll 1
  for (int nt = 0; nt < 8; ++nt) {
    f32x16 a00 = 0.0f, a01 = 0.0f, a10 = 0.0f, a11 = 0.0f;
#pragma unroll
    for (int kt = 0; kt < 8; ++kt) {
      const int cur = kt & 1;
      if (kt < 7)      stage(cur ^ 1, nt, kt + 1);
      else if (nt < 7) stage(cur ^ 1, nt + 1, 0);

#pragma unroll
      for (int ks = 0; ks < 2; ++ks) {
        const int s  = ks * 2 + (lane >> 5);
        const int ra = lane & 31;
        auto frag = [&](int tile, int row) -> s16x8 {
          int slot = s ^ (row & 3) ^ ((row >> 2) & 1);
          return *(const s16x8*)(&smem[cur][tile][0] + row * 64 + slot * 16);
        };
        s16x8 ah0 = frag(0, wm * 64 + ra);
        s16x8 ah1 = frag(0, wm * 64 + 32 + ra);
        s16x8 al0 = frag(1, wm * 64 + ra);
        s16x8 al1 = frag(1, wm * 64 + 32 + ra);
        s16x8 bh0 = frag(2, wn * 64 + ra);
        s16x8 bh1 = frag(2, wn * 64 + 32 + ra);
        s16x8 bl0 = frag(3, wn * 64 + ra);
        s16x8 bl1 = frag(3, wn * 64 + 32 + ra);
        a00 = __builtin_amdgcn_mfma_f32_32x32x16_bf16(ah0, bh0, a00, 0, 0, 0);
        a01 = __builtin_amdgcn_mfma_f32_32x32x16_bf16(ah0, bh1, a01, 0, 0, 0);
        a10 = __builtin_amdgcn_mfma_f32_32x32x16_bf16(ah1, bh0, a10, 0, 0, 0);
        a11 = __builtin_amdgcn_mfma_f32_32x32x16_bf16(ah1, bh1, a11, 0, 0, 0);
        a00 = __builtin_amdgcn_mfma_f32_32x32x16_bf16(al0, bh0, a00, 0, 0, 0);
        a01 = __builtin_amdgcn_mfma_f32_32x32x16_bf16(al0, bh1, a01, 0, 0, 0);
        a10 = __builtin_amdgcn_mfma_f32_32x32x16_bf16(al1, bh0, a10, 0, 0, 0);
        a11 = __builtin_amdgcn_mfma_f32_32x32x16_bf16(al1, bh1, a11, 0, 0, 0);
        a00 = __builtin_amdgcn_mfma_f32_32x32x16_bf16(ah0, bl0, a00, 0, 0, 0);
        a01 = __builtin_amdgcn_mfma_f32_32x32x16_bf16(ah0, bl1, a01, 0, 0, 0);
        a10 = __builtin_amdgcn_mfma_f32_32x32x16_bf16(ah1, bl0, a10, 0, 0, 0);
        a11 = __builtin_amdgcn_mfma_f32_32x32x16_bf16(ah1, bl1, a11, 0, 0, 0);
      }
      __syncthreads();
    }

    // fold this nt's codes into running per-lane (m1, m2, i1) state
    const int cbase = nt * 128 + wn * 64 + (lane & 31);
#define FOLD(IDX, V, C)                                                        \
    {                                                                          \
      float v_ = (V);                                                          \
      if (v_ > m1[IDX]) { m2[IDX] = m1[IDX]; m1[IDX] = v_; i1[IDX] = (C); }    \
      else              { m2[IDX] = fmaxf(m2[IDX], v_); }                      \
    }
#pragma unroll
    for (int p = 0; p < 16; ++p) {
      FOLD(p,      a00[p], cbase);
      FOLD(p,      a01[p], cbase + 32);
      FOLD(16 + p, a10[p], cbase);
      FOLD(16 + p, a11[p], cbase + 32);
    }
#undef FOLD
  }

  // ---- cross-lane reduce over the 32 column-lanes (within wave) ----
#pragma unroll
  for (int off = 1; off <= 16; off <<= 1) {
#pragma unroll
    for (int idx = 0; idx < 32; ++idx) {
      float om1 = __shfl_xor(m1[idx], off);
      float om2 = __shfl_xor(m2[idx], off);
      int   oi1 = __shfl_xor(i1[idx], off);
      if (om1 > m1[idx] || (om1 == m1[idx] && oi1 < i1[idx])) {
        m2[idx] = fmaxf(m1[idx], om2);
        m1[idx] = om1; i1[idx] = oi1;
      } else {
        m2[idx] = fmaxf(m2[idx], om1);
      }
    }
  }

  // ---- cross-wn merge: wn=1 publishes, wn=0 merges + writes ----
  if (wn == 1 && (lane & 31) == 0) {
    const int half = lane >> 5;
#pragma unroll
    for (int idx = 0; idx < 32; ++idx) {
      xm1[wm][half][idx] = m1[idx];
      xm2[wm][half][idx] = m2[idx];
      xi1[wm][half][idx] = i1[idx];
    }
  }
  __syncthreads();
  if (wn == 0 && (lane & 31) == 0) {
    const int half = lane >> 5;
#pragma unroll
    for (int idx = 0; idx < 32; ++idx) {
      float om1 = xm1[wm][half][idx];
      float om2 = xm2[wm][half][idx];
      int   oi1 = xi1[wm][half][idx];
      if (om1 > m1[idx] || (om1 == m1[idx] && oi1 < i1[idx])) {
        m2[idx] = fmaxf(m1[idx], om2);
        m1[idx] = om1; i1[idx] = oi1;
      } else {
        m2[idx] = fmaxf(m2[idx], om1);
      }
    }
#pragma unroll
    for (int idx = 0; idx < 32; ++idx) {
      int p = idx & 15;
      int lrow = wm * 64 + (idx >> 4) * 32 + (p & 3) + 8 * (p >> 2) + 4 * half;
      int row  = mtile * 128 + lrow;
      sidx[lrow]   = i1[idx];
      idx_int[row] = i1[idx];
      out_idx[row] = (float)i1[idx];
      if (m1[idx] - m2[idx] < MARGIN) {
        int pos = atomicAdd(flagc, 1);
        flagr[pos] = row;
      }
    }
  }
  __syncthreads();

  // ---- fused gather: z_q write, mse partial, counts ----
  double msum = 0.0;
  for (int rr = w; rr < 128; rr += 4) {
    const int code = sidx[rr];
    const int grow = mtile * 128 + rr;
    float4 c = *(const float4*)&cb32[(size_t)code * 256 + lane * 4];
    *(float4*)&zq[(size_t)grow * 256 + lane * 4] = c;
    float4 zr;
    if (PRESPLIT) {
      ushort4 h = *(const ushort4*)&zhi[(size_t)grow * 256 + lane * 4];
      ushort4 l = *(const ushort4*)&zlo[(size_t)grow * 256 + lane * 4];
      zr.x = bf2f(h.x) + bf2f(l.x);
      zr.y = bf2f(h.y) + bf2f(l.y);
      zr.z = bf2f(h.z) + bf2f(l.z);
      zr.w = bf2f(h.w) + bf2f(l.w);
    } else {
      zr = *(const float4*)&z[(size_t)grow * 256 + lane * 4];
    }
    double d;
    d = (double)c.x - (double)zr.x; msum += d * d;
    d = (double)c.y - (double)zr.y; msum += d * d;
    d = (double)c.z - (double)zr.z; msum += d * d;
    d = (double)c.w - (double)zr.w; msum += d * d;
    if (lane == 0) atomicAdd(&counts[code], 1);
  }
#pragma unroll
  for (int off = 32; off > 0; off >>= 1) msum += __shfl_xor(msum, off);
  if (lane == 0) partial[w] = msum;
  __syncthreads();
  if (t == 0) msep[mtile] = partial[0] + partial[1] + partial[2] + partial[3];
}

// ---------------------------------------------------------------------------
// Kernel 3: exact fp64 re-solve of flagged rows; patches idx, z_q, counts,
// and accumulates the mse delta for rows whose index changes.
// ---------------------------------------------------------------------------
__global__ __launch_bounds__(256) void refine_kernel(const float* __restrict__ z,
                                                     const double* __restrict__ cb64,
                                                     const double* __restrict__ c264,
                                                     const float* __restrict__ cb32,
                                                     const int* __restrict__ flagc,
                                                     const int* __restrict__ flagr,
                                                     int* __restrict__ idx_int,
                                                     float* __restrict__ out_idx,
                                                     float* __restrict__ zq,
                                                     int* __restrict__ counts,
                                                     double* __restrict__ msedelta) {
  const int cnt  = *flagc;
  const int t    = threadIdx.x;
  const int w    = t >> 6;
  const int lane = t & 63;
  __shared__ double bs[4];
  __shared__ int    bi[4];
  __shared__ int    shI, shO;
  __shared__ double red[256];

  for (int fi = blockIdx.x; fi < cnt; fi += gridDim.x) {
    const int row = flagr[fi];
    double zr[4];
#pragma unroll
    for (int jj = 0; jj < 4; ++jj)
      zr[jj] = (double)z[row * DDIM + jj * 64 + lane];

    double best = -1e300;
    int bidx = 0;
    for (int k = w * 256; k < w * 256 + 256; ++k) {
      double p = 0.0;
#pragma unroll
      for (int jj = 0; jj < 4; ++jj)
        p += zr[jj] * cb64[k * DDIM + jj * 64 + lane];
#pragma unroll
      for (int off = 32; off > 0; off >>= 1) p += __shfl_xor(p, off);
      double sc = 2.0 * p - c264[k];
      if (sc > best) { best = sc; bidx = k; }   // ascending k: tie -> smaller
    }
    if (lane == 0) { bs[w] = best; bi[w] = bidx; }
    __syncthreads();
    if (t == 0) {
      double B = bs[0]; int I = bi[0];
#pragma unroll
      for (int w2 = 1; w2 < 4; ++w2) {
        if (bs[w2] > B || (bs[w2] == B && bi[w2] < I)) { B = bs[w2]; I = bi[w2]; }
      }
      shO = idx_int[row];
      shI = I;
      if (I != shO) {
        idx_int[row] = I;
        out_idx[row] = (float)I;
        atomicSub(&counts[shO], 1);
        atomicAdd(&counts[I], 1);
      }
    }
    __syncthreads();
    const int I = shI, O = shO;
    if (I != O) {
      float zz = z[row * DDIM + t];
      float cn = cb32[I * DDIM + t];
      float co = cb32[O * DDIM + t];
      zq[(size_t)row * DDIM + t] = cn;
      double dn = (double)cn - (double)zz;
      double dd = (double)co - (double)zz;
      red[t] = dn * dn - dd * dd;
      __syncthreads();
      for (int s = 128; s > 0; s >>= 1) {
        if (t < s) red[t] += red[t + s];
        __syncthreads();
      }
      if (t == 0) atomicAdd(msedelta, red[0]);
    }
    __syncthreads();
  }
}

// ---------------------------------------------------------------------------
// Kernel 4: scalars -- vq_loss, perplexity, codebook_usage.
// ---------------------------------------------------------------------------
__global__ __launch_bounds__(256) void finalize_kernel(const int* __restrict__ counts,
                                                       const double* __restrict__ msep,
                                                       const double* __restrict__ msedelta,
                                                       float* __restrict__ out) {
  const int t = threadIdx.x;
  double ms = 0.0;
#pragma unroll
  for (int i = t; i < 512; i += 256) ms += msep[i];
  if (t == 0) ms += *msedelta;

  double ent = 0.0;
  int used = 0;
#pragma unroll
  for (int i = t; i < KCB; i += 256) {
    int c = counts[i];
    if (c > 0) used++;
    double p = (double)c / (double)NROWS;
    ent += p * log(p + 1e-10);
  }
  __shared__ double se[256];
  __shared__ double sm[256];
  __shared__ int    su[256];
  se[t] = ent; sm[t] = ms; su[t] = used;
  __syncthreads();
  for (int s = 128; s > 0; s >>= 1) {
    if (t < s) { se[t] += se[t + s]; sm[t] += sm[t + s]; su[t] += su[t + s]; }
    __syncthreads();
  }
  if (t == 0) {
    double mse = sm[0] / ((double)NROWS * (double)DDIM);
    out[OUT_LOSS]  = (float)(1.25 * mse);
    out[OUT_PERP]  = (float)exp(-se[0]);
    out[OUT_USAGE] = (float)((double)su[0] / (double)KCB);
  }
}

// ---------------------------------------------------------------------------
extern "C" void kernel_launch(void* const* d_in, const int* in_sizes, int n_in,
                              void* d_out, int out_size, void* d_ws, size_t ws_size,
                              hipStream_t stream) {
  const float* z  = (const float*)d_in[0];   // [65536][256]
  const float* lb = (const float*)d_in[1];   // [1024][256]
  const float* W  = (const float*)d_in[2];   // [256][256]
  float* out = (float*)d_out;

  const size_t NEEDED_FULL = 0x4490000;      // ~72 MB incl. z_hi/z_lo
  const bool presplit = ws_size >= NEEDED_FULL;

  char* ws = (char*)d_ws;
  ushort* zhi = (ushort*)(ws + 0x0000000);   // 32 MB (presplit only)
  ushort* zlo = (ushort*)(ws + 0x2000000);   // 32 MB (presplit only)
  char* base = ws + (presplit ? 0x4000000 : 0);

  double* cb64    = (double*)(base + 0x000000);  // 2 MB
  ushort* ch      = (ushort*)(base + 0x200000);  // 512 KB
  ushort* cl      = (ushort*)(base + 0x280000);  // 512 KB
  float*  cb32    = (float*) (base + 0x300000);  // 1 MB
  double* c264    = (double*)(base + 0x400000);  // 8 KB
  int*    idxi    = (int*)   (base + 0x402000);  // 256 KB
  int*    flagr   = (int*)   (base + 0x442000);  // 256 KB
  int*    flagc   = (int*)   (base + 0x482000);  // 4 B
  int*    counts  = (int*)   (base + 0x482100);  // 4 KB
  double* msep    = (double*)(base + 0x483100);  // 4 KB (512 doubles)
  double* msedel  = (double*)(base + 0x484100);  // 8 B

  hipMemsetAsync(flagc, 0, 4, stream);
  hipMemsetAsync(counts, 0, KCB * sizeof(int), stream);
  hipMemsetAsync(msedel, 0, sizeof(double), stream);

  cb_kernel<<<KCB, 256, 0, stream>>>(lb, W, cb64, cb32, c264, ch, cl);
  if (presplit) {
    zsplit_kernel<<<4096, 256, 0, stream>>>(z, zhi, zlo);
    argmax_mfma<true><<<NROWS / 128, 256, 0, stream>>>(z, zhi, zlo, ch, cl, cb32,
                                                       out + OUT_IDX, idxi, flagc, flagr,
                                                       out + OUT_ZQ, msep, counts);
  } else {
    argmax_mfma<false><<<NROWS / 128, 256, 0, stream>>>(z, zhi, zlo, ch, cl, cb32,
                                                        out + OUT_IDX, idxi, flagc, flagr,
                                                        out + OUT_ZQ, msep, counts);
  }
  refine_kernel<<<512, 256, 0, stream>>>(z, cb64, c264, cb32, flagc, flagr,
                                         idxi, out + OUT_IDX, out + OUT_ZQ,
                                         counts, msedel);
  finalize_kernel<<<1, 256, 0, stream>>>(counts, msep, msedel, out);
}

// Round 6
// 311.173 us; speedup vs baseline: 13.1949x; 11.5995x over previous
//
#include <hip/hip_runtime.h>
#include <math.h>

typedef unsigned int uint;
typedef unsigned short ushort;

#define NROWS 65536
#define KCB   1024
#define DDIM  256
#define MARGIN 0.01f

// d_out layout (floats)
#define OUT_ZQ    0
#define OUT_LOSS  16777216
#define OUT_IDX   16777217
#define OUT_PERP  16842753
#define OUT_USAGE 16842754

typedef __attribute__((ext_vector_type(8)))  short s16x8;
typedef __attribute__((ext_vector_type(16))) float f32x16;

__device__ __forceinline__ ushort bf16rne(float x) {
  uint u = __float_as_uint(x);
  return (ushort)((u + 0x7FFFu + ((u >> 16) & 1u)) >> 16);
}
__device__ __forceinline__ float bf2f(ushort h) {
  return __uint_as_float((uint)h << 16);
}

// ---------------------------------------------------------------------------
// Kernel 1: codebook = normalize(lb @ W.T) * 16 in fp64; emit fp64, fp32,
// and bf16 hi/lo split copies.
// ---------------------------------------------------------------------------
__global__ __launch_bounds__(256) void cb_kernel(const float* __restrict__ lb,
                                                 const float* __restrict__ W,
                                                 double* __restrict__ cb64,
                                                 float* __restrict__ cb32,
                                                 double* __restrict__ c264,
                                                 ushort* __restrict__ ch,
                                                 ushort* __restrict__ cl) {
  const int k = blockIdx.x;
  const int t = threadIdx.x;
  __shared__ float lb_sh[256];
  __shared__ float W_sh[256 * 66];
  __shared__ double red[256];

  lb_sh[t] = lb[k * 256 + t];

  double acc = 0.0;
  for (int jt = 0; jt < 4; ++jt) {
    __syncthreads();
#pragma unroll
    for (int i = 0; i < 16; ++i) {
      int qid = t + 256 * i;
      int row = qid >> 4;
      int q   = qid & 15;
      float4 v = *(const float4*)&W[row * 256 + jt * 64 + q * 4];
      float* dst = &W_sh[row * 66 + q * 4];
      dst[0] = v.x; dst[1] = v.y; dst[2] = v.z; dst[3] = v.w;
    }
    __syncthreads();
#pragma unroll
    for (int jj = 0; jj < 64; ++jj) {
      acc += (double)lb_sh[jt * 64 + jj] * (double)W_sh[t * 66 + jj];
    }
  }

  red[t] = acc * acc;
  __syncthreads();
  for (int s = 128; s > 0; s >>= 1) {
    if (t < s) red[t] += red[t + s];
    __syncthreads();
  }
  double norm  = sqrt(red[0]);
  double scale = 16.0 / fmax(norm, 1e-12);
  double v     = acc * scale;
  cb64[k * 256 + t] = v;
  float cf = (float)v;
  cb32[k * 256 + t] = cf;
  ushort hh = bf16rne(cf);
  ch[k * 256 + t] = hh;
  cl[k * 256 + t] = bf16rne(cf - bf2f(hh));

  __syncthreads();
  red[t] = v * v;
  __syncthreads();
  for (int s = 128; s > 0; s >>= 1) {
    if (t < s) red[t] += red[t + s];
    __syncthreads();
  }
  if (t == 0) c264[k] = red[0];
}

// ---------------------------------------------------------------------------
// Kernel 1b: split z fp32 -> z_hi + z_lo bf16.
// ---------------------------------------------------------------------------
__global__ __launch_bounds__(256) void zsplit_kernel(const float* __restrict__ z,
                                                     ushort* __restrict__ zhi,
                                                     ushort* __restrict__ zlo) {
  int i = blockIdx.x * 256 + threadIdx.x;
  const int stride = gridDim.x * 256;
  const int nq = NROWS * DDIM / 4;
  for (; i < nq; i += stride) {
    float4 v = *(const float4*)&z[i * 4];
    ushort4 h, l;
    h.x = bf16rne(v.x); l.x = bf16rne(v.x - bf2f(h.x));
    h.y = bf16rne(v.y); l.y = bf16rne(v.y - bf2f(h.y));
    h.z = bf16rne(v.z); l.z = bf16rne(v.z - bf2f(h.z));
    h.w = bf16rne(v.w); l.w = bf16rne(v.w - bf2f(h.w));
    *(ushort4*)&zhi[i * 4] = h;
    *(ushort4*)&zlo[i * 4] = l;
  }
}

// ---------------------------------------------------------------------------
// Kernel 2: fused MFMA argmax + gather, SWAPPED OPERANDS (round-6 rewrite).
// D = cb . z^T : D[code][zrow], C/D layout col=lane&31 -> zrow, codes across
// the 16 acc regs. Each lane owns ONE z-row => running argmax state is a
// single (m1,m2,i1) triple (3 VGPRs) -- round 5's 96-reg state spilled to
// scratch (11 GB of HBM scratch traffic, the 3.4 ms regression).
// z fragments (B operand) loaded ONCE into 128 VGPRs; inner loop stages only
// the 8 KB cb tile (double-buffered, 2 global_load_lds per wave per step).
// Block = 128 z-rows (4 waves x 32) x all 1024 codes (16 nt-tiles of 64).
// ---------------------------------------------------------------------------
template <bool PRESPLIT>
__global__ __launch_bounds__(256, 2) void argmax_mfma(const float* __restrict__ z,
                                                      const ushort* __restrict__ zhi,
                                                      const ushort* __restrict__ zlo,
                                                      const ushort* __restrict__ ch,
                                                      const ushort* __restrict__ cl,
                                                      const float* __restrict__ cb32,
                                                      float* __restrict__ out_idx,
                                                      int* __restrict__ idx_int,
                                                      int* __restrict__ flagc,
                                                      int* __restrict__ flagr,
                                                      float* __restrict__ zq,
                                                      double* __restrict__ msep,
                                                      int* __restrict__ counts) {
  const int t     = threadIdx.x;
  const int lane  = t & 63;
  const int w     = t >> 6;
  const int h     = lane >> 5;     // k-slot half
  const int ra    = lane & 31;
  const int mtile = blockIdx.x;

  __shared__ alignas(128) char cbuf[2][8192];  // [buf]: CH @0, CL @4096
  __shared__ int    sidx[128];
  __shared__ double partial[4];

  // ---- z fragments: one z-row per lane, full K=256 in registers ----
  s16x8 zh[16], zl[16];
  const int zrow = mtile * 128 + w * 32 + ra;
  if (PRESPLIT) {
#pragma unroll
    for (int s = 0; s < 16; ++s) {
      zh[s] = *(const s16x8*)&zhi[(size_t)zrow * 256 + s * 16 + h * 8];
      zl[s] = *(const s16x8*)&zlo[(size_t)zrow * 256 + s * 16 + h * 8];
    }
  } else {
#pragma unroll
    for (int s = 0; s < 16; ++s) {
      const float* zp = &z[(size_t)zrow * 256 + s * 16 + h * 8];
      float4 f0 = *(const float4*)zp;
      float4 f1 = *(const float4*)(zp + 4);
      float xs[8] = {f0.x, f0.y, f0.z, f0.w, f1.x, f1.y, f1.z, f1.w};
#pragma unroll
      for (int e = 0; e < 8; ++e) {
        ushort hh = bf16rne(xs[e]);
        zh[s][e] = (short)hh;
        zl[s][e] = (short)bf16rne(xs[e] - bf2f(hh));
      }
    }
  }

  // ---- cb tile staging: 64 codes x 32 k, hi+lo = 8 KB per step ----
  // linear LDS dest (wave-uniform base + lane*16), swizzle on global source:
  // LDS[tile][row][q] holds global slot q ^ (row&3) ^ ((row>>2)&1).
  auto stage = [&](int buf, int nt, int kt) {
#pragma unroll
    for (int j = 0; j < 2; ++j) {
      int sid  = w * 128 + j * 64 + lane;     // 512 slots of 16 B
      int tile = sid >> 8;                    // 0=CH, 1=CL
      int row  = (sid & 255) >> 2;
      int q    = sid & 3;
      int qs   = q ^ (row & 3) ^ ((row >> 2) & 1);
      const ushort* sb  = tile ? cl : ch;
      const ushort* src = sb + (size_t)(nt * 64 + row) * 256 + kt * 32 + qs * 8;
      __builtin_amdgcn_global_load_lds((const __attribute__((address_space(1))) void*)src,
                                       (__attribute__((address_space(3))) void*)(&cbuf[buf][0] + w * 2048 + j * 1024),
                                       16, 0, 0);
    }
  };

  float m1 = -3.0e38f, m2 = -3.0e38f;
  int   i1 = 0;

  stage(0, 0, 0);
  __syncthreads();

#pragma unroll 1
  for (int nt = 0; nt < 16; ++nt) {
    f32x16 acc0 = 0.0f, acc1 = 0.0f;
#pragma unroll
    for (int kt = 0; kt < 8; ++kt) {
      const int cur = kt & 1;
      if (kt < 7)       stage(cur ^ 1, nt, kt + 1);
      else if (nt < 15) stage(cur ^ 1, nt + 1, 0);

#pragma unroll
      for (int ks = 0; ks < 2; ++ks) {
        const int s = ks * 2 + h;
        auto afrag = [&](int tile, int row) -> s16x8 {
          int slot = s ^ (row & 3) ^ ((row >> 2) & 1);
          return *(const s16x8*)(&cbuf[cur][0] + tile * 4096 + row * 64 + slot * 16);
        };
        s16x8 ah0 = afrag(0, ra);
        s16x8 ah1 = afrag(0, 32 + ra);
        s16x8 al0 = afrag(1, ra);
        s16x8 al1 = afrag(1, 32 + ra);
        const s16x8 bh = zh[kt * 2 + ks];
        const s16x8 bl = zl[kt * 2 + ks];
        acc0 = __builtin_amdgcn_mfma_f32_32x32x16_bf16(ah0, bh, acc0, 0, 0, 0);
        acc1 = __builtin_amdgcn_mfma_f32_32x32x16_bf16(ah1, bh, acc1, 0, 0, 0);
        acc0 = __builtin_amdgcn_mfma_f32_32x32x16_bf16(al0, bh, acc0, 0, 0, 0);
        acc1 = __builtin_amdgcn_mfma_f32_32x32x16_bf16(al1, bh, acc1, 0, 0, 0);
        acc0 = __builtin_amdgcn_mfma_f32_32x32x16_bf16(ah0, bl, acc0, 0, 0, 0);
        acc1 = __builtin_amdgcn_mfma_f32_32x32x16_bf16(ah1, bl, acc1, 0, 0, 0);
      }
      __syncthreads();
    }

    // fold this nt's 64 codes into the lane's single (m1, m2, i1) state.
    // D-row (code) = (p&3) + 8*(p>>2) + 4*h  (+32 for acc1), col = zrow.
#pragma unroll
    for (int p = 0; p < 16; ++p) {
      const int crow = (p & 3) + 8 * (p >> 2) + 4 * h;
      const int c0   = nt * 64 + crow;
      float v0 = acc0[p];
      if (v0 > m1) { m2 = m1; m1 = v0; i1 = c0; }
      else         { m2 = fmaxf(m2, v0); }
      float v1 = acc1[p];
      if (v1 > m1) { m2 = m1; m1 = v1; i1 = c0 + 32; }
      else         { m2 = fmaxf(m2, v1); }
    }
  }

  // ---- single cross-lane merge: lane <-> lane^32 (code halves) ----
  {
    float om1 = __shfl_xor(m1, 32);
    float om2 = __shfl_xor(m2, 32);
    int   oi1 = __shfl_xor(i1, 32);
    if (om1 > m1 || (om1 == m1 && oi1 < i1)) {
      m2 = fmaxf(m1, om2); m1 = om1; i1 = oi1;
    } else {
      m2 = fmaxf(m2, om1);
    }
  }

  if (lane < 32) {
    const int row = mtile * 128 + w * 32 + lane;
    sidx[w * 32 + lane] = i1;
    idx_int[row] = i1;
    out_idx[row] = (float)i1;
    if (m1 - m2 < MARGIN) {
      int pos = atomicAdd(flagc, 1);
      flagr[pos] = row;
    }
  }
  __syncthreads();

  // ---- fused gather: z_q write, mse partial, counts ----
  double msum = 0.0;
  for (int rr = w; rr < 128; rr += 4) {
    const int code = sidx[rr];
    const int grow = mtile * 128 + rr;
    float4 c = *(const float4*)&cb32[(size_t)code * 256 + lane * 4];
    *(float4*)&zq[(size_t)grow * 256 + lane * 4] = c;
    float4 zr;
    if (PRESPLIT) {
      ushort4 hh = *(const ushort4*)&zhi[(size_t)grow * 256 + lane * 4];
      ushort4 ll = *(const ushort4*)&zlo[(size_t)grow * 256 + lane * 4];
      zr.x = bf2f(hh.x) + bf2f(ll.x);
      zr.y = bf2f(hh.y) + bf2f(ll.y);
      zr.z = bf2f(hh.z) + bf2f(ll.z);
      zr.w = bf2f(hh.w) + bf2f(ll.w);
    } else {
      zr = *(const float4*)&z[(size_t)grow * 256 + lane * 4];
    }
    double d;
    d = (double)c.x - (double)zr.x; msum += d * d;
    d = (double)c.y - (double)zr.y; msum += d * d;
    d = (double)c.z - (double)zr.z; msum += d * d;
    d = (double)c.w - (double)zr.w; msum += d * d;
    if (lane == 0) atomicAdd(&counts[code], 1);
  }
#pragma unroll
  for (int off = 32; off > 0; off >>= 1) msum += __shfl_xor(msum, off);
  if (lane == 0) partial[w] = msum;
  __syncthreads();
  if (t == 0) msep[mtile] = partial[0] + partial[1] + partial[2] + partial[3];
}

// ---------------------------------------------------------------------------
// Kernel 3: exact fp64 re-solve of flagged rows; patches idx, z_q, counts,
// and accumulates the mse delta for rows whose index changes.
// ---------------------------------------------------------------------------
__global__ __launch_bounds__(256) void refine_kernel(const float* __restrict__ z,
                                                     const double* __restrict__ cb64,
                                                     const double* __restrict__ c264,
                                                     const float* __restrict__ cb32,
                                                     const int* __restrict__ flagc,
                                                     const int* __restrict__ flagr,
                                                     int* __restrict__ idx_int,
                                                     float* __restrict__ out_idx,
                                                     float* __restrict__ zq,
                                                     int* __restrict__ counts,
                                                     double* __restrict__ msedelta) {
  const int cnt  = *flagc;
  const int t    = threadIdx.x;
  const int w    = t >> 6;
  const int lane = t & 63;
  __shared__ double bs[4];
  __shared__ int    bi[4];
  __shared__ int    shI, shO;
  __shared__ double red[256];

  for (int fi = blockIdx.x; fi < cnt; fi += gridDim.x) {
    const int row = flagr[fi];
    double zr[4];
#pragma unroll
    for (int jj = 0; jj < 4; ++jj)
      zr[jj] = (double)z[row * DDIM + jj * 64 + lane];

    double best = -1e300;
    int bidx = 0;
    for (int k = w * 256; k < w * 256 + 256; ++k) {
      double p = 0.0;
#pragma unroll
      for (int jj = 0; jj < 4; ++jj)
        p += zr[jj] * cb64[k * DDIM + jj * 64 + lane];
#pragma unroll
      for (int off = 32; off > 0; off >>= 1) p += __shfl_xor(p, off);
      double sc = 2.0 * p - c264[k];
      if (sc > best) { best = sc; bidx = k; }   // ascending k: tie -> smaller
    }
    if (lane == 0) { bs[w] = best; bi[w] = bidx; }
    __syncthreads();
    if (t == 0) {
      double B = bs[0]; int I = bi[0];
#pragma unroll
      for (int w2 = 1; w2 < 4; ++w2) {
        if (bs[w2] > B || (bs[w2] == B && bi[w2] < I)) { B = bs[w2]; I = bi[w2]; }
      }
      shO = idx_int[row];
      shI = I;
      if (I != shO) {
        idx_int[row] = I;
        out_idx[row] = (float)I;
        atomicSub(&counts[shO], 1);
        atomicAdd(&counts[I], 1);
      }
    }
    __syncthreads();
    const int I = shI, O = shO;
    if (I != O) {
      float zz = z[row * DDIM + t];
      float cn = cb32[I * DDIM + t];
      float co = cb32[O * DDIM + t];
      zq[(size_t)row * DDIM + t] = cn;
      double dn = (double)cn - (double)zz;
      double dd = (double)co - (double)zz;
      red[t] = dn * dn - dd * dd;
      __syncthreads();
      for (int s = 128; s > 0; s >>= 1) {
        if (t < s) red[t] += red[t + s];
        __syncthreads();
      }
      if (t == 0) atomicAdd(msedelta, red[0]);
    }
    __syncthreads();
  }
}

// ---------------------------------------------------------------------------
// Kernel 4: scalars -- vq_loss, perplexity, codebook_usage.
// ---------------------------------------------------------------------------
__global__ __launch_bounds__(256) void finalize_kernel(const int* __restrict__ counts,
                                                       const double* __restrict__ msep,
                                                       const double* __restrict__ msedelta,
                                                       float* __restrict__ out) {
  const int t = threadIdx.x;
  double ms = 0.0;
#pragma unroll
  for (int i = t; i < 512; i += 256) ms += msep[i];
  if (t == 0) ms += *msedelta;

  double ent = 0.0;
  int used = 0;
#pragma unroll
  for (int i = t; i < KCB; i += 256) {
    int c = counts[i];
    if (c > 0) used++;
    double p = (double)c / (double)NROWS;
    ent += p * log(p + 1e-10);
  }
  __shared__ double se[256];
  __shared__ double sm[256];
  __shared__ int    su[256];
  se[t] = ent; sm[t] = ms; su[t] = used;
  __syncthreads();
  for (int s = 128; s > 0; s >>= 1) {
    if (t < s) { se[t] += se[t + s]; sm[t] += sm[t + s]; su[t] += su[t + s]; }
    __syncthreads();
  }
  if (t == 0) {
    double mse = sm[0] / ((double)NROWS * (double)DDIM);
    out[OUT_LOSS]  = (float)(1.25 * mse);
    out[OUT_PERP]  = (float)exp(-se[0]);
    out[OUT_USAGE] = (float)((double)su[0] / (double)KCB);
  }
}

// ---------------------------------------------------------------------------
extern "C" void kernel_launch(void* const* d_in, const int* in_sizes, int n_in,
                              void* d_out, int out_size, void* d_ws, size_t ws_size,
                              hipStream_t stream) {
  const float* z  = (const float*)d_in[0];   // [65536][256]
  const float* lb = (const float*)d_in[1];   // [1024][256]
  const float* W  = (const float*)d_in[2];   // [256][256]
  float* out = (float*)d_out;

  const size_t NEEDED_FULL = 0x4490000;      // ~72 MB incl. z_hi/z_lo
  const bool presplit = ws_size >= NEEDED_FULL;

  char* ws = (char*)d_ws;
  ushort* zhi = (ushort*)(ws + 0x0000000);   // 32 MB (presplit only)
  ushort* zlo = (ushort*)(ws + 0x2000000);   // 32 MB (presplit only)
  char* base = ws + (presplit ? 0x4000000 : 0);

  double* cb64    = (double*)(base + 0x000000);  // 2 MB
  ushort* ch      = (ushort*)(base + 0x200000);  // 512 KB
  ushort* cl      = (ushort*)(base + 0x280000);  // 512 KB
  float*  cb32    = (float*) (base + 0x300000);  // 1 MB
  double* c264    = (double*)(base + 0x400000);  // 8 KB
  int*    idxi    = (int*)   (base + 0x402000);  // 256 KB
  int*    flagr   = (int*)   (base + 0x442000);  // 256 KB
  int*    flagc   = (int*)   (base + 0x482000);  // 4 B
  int*    counts  = (int*)   (base + 0x482100);  // 4 KB
  double* msep    = (double*)(base + 0x483100);  // 4 KB (512 doubles)
  double* msedel  = (double*)(base + 0x484100);  // 8 B

  hipMemsetAsync(flagc, 0, 4, stream);
  hipMemsetAsync(counts, 0, KCB * sizeof(int), stream);
  hipMemsetAsync(msedel, 0, sizeof(double), stream);

  cb_kernel<<<KCB, 256, 0, stream>>>(lb, W, cb64, cb32, c264, ch, cl);
  if (presplit) {
    zsplit_kernel<<<4096, 256, 0, stream>>>(z, zhi, zlo);
    argmax_mfma<true><<<NROWS / 128, 256, 0, stream>>>(z, zhi, zlo, ch, cl, cb32,
                                                       out + OUT_IDX, idxi, flagc, flagr,
                                                       out + OUT_ZQ, msep, counts);
  } else {
    argmax_mfma<false><<<NROWS / 128, 256, 0, stream>>>(z, zhi, zlo, ch, cl, cb32,
                                                        out + OUT_IDX, idxi, flagc, flagr,
                                                        out + OUT_ZQ, msep, counts);
  }
  refine_kernel<<<512, 256, 0, stream>>>(z, cb64, c264, cb32, flagc, flagr,
                                         idxi, out + OUT_IDX, out + OUT_ZQ,
                                         counts, msedel);
  finalize_kernel<<<1, 256, 0, stream>>>(counts, msep, msedel, out);
}